// Round 2
// baseline (268.843 us; speedup 1.0000x reference)
//
#include <hip/hip_runtime.h>
#include <stdint.h>

typedef __bf16 bf16x8 __attribute__((ext_vector_type(8)));
typedef float f32x4 __attribute__((ext_vector_type(4)));
typedef float f32x16 __attribute__((ext_vector_type(16)));
typedef short s16x4 __attribute__((ext_vector_type(4)));

#define HAS_X8 __has_builtin(__builtin_amdgcn_mfma_f32_32x32x8bf16_1k)

static __device__ __forceinline__ unsigned int pk_bf16(float a, float b) {
  unsigned int d;
  asm("v_cvt_pk_bf16_f32 %0, %1, %2" : "=v"(d) : "v"(a), "v"(b));
  return d;
}
static __device__ __forceinline__ float exp2_hw(float x) {
  float r;
  asm("v_exp_f32 %0, %1" : "=v"(r) : "v"(x));
  return r;
}
static __device__ __forceinline__ float rcp_hw(float x) {
  float r;
  asm("v_rcp_f32 %0, %1" : "=v"(r) : "v"(x));
  return r;
}
static __device__ __forceinline__ void gll16(const void* g, void* l) {
  __builtin_amdgcn_global_load_lds((const __attribute__((address_space(1))) unsigned int*)g,
                                   (__attribute__((address_space(3))) unsigned int*)l,
                                   16, 0, 0);
}

// ============================================================
// Kernel 0: fused prep.  blocks [0,8192): X f32 -> bf16 (4/thread)
//           blocks [8192,11264): W_eff = W + (1/16) B@A (4/thread)
// ============================================================
__global__ __launch_bounds__(256) void prep_kernel(
    const float* __restrict__ X, unsigned short* __restrict__ Xbf,
    const float* __restrict__ Wq, const float* __restrict__ Aq, const float* __restrict__ Bq,
    const float* __restrict__ Wk, const float* __restrict__ Ak, const float* __restrict__ Bk,
    const float* __restrict__ Wv, const float* __restrict__ Av, const float* __restrict__ Bv,
    unsigned short* __restrict__ Weff) {
  int bid = blockIdx.x;
  if (bid < 8192) {
    int i = (bid * 256 + threadIdx.x) * 4;
    float4 v = *(const float4*)(X + i);
    uint2 o;
    o.x = pk_bf16(v.x, v.y);
    o.y = pk_bf16(v.z, v.w);
    *(uint2*)(Xbf + i) = o;
  } else {
    int idx = ((bid - 8192) * 256 + threadIdx.x) * 4;
    int p = idx >> 20;
    int o = (idx >> 10) & 1023;
    int i = idx & 1023;
    const float* W = (p == 0) ? Wq : (p == 1) ? Wk : Wv;
    const float* A = (p == 0) ? Aq : (p == 1) ? Ak : Av;
    const float* B = (p == 0) ? Bq : (p == 1) ? Bk : Bv;
    float4 acc = {0.f, 0.f, 0.f, 0.f};
#pragma unroll
    for (int r = 0; r < 16; ++r) {
      float bb = B[o * 16 + r];
      float4 av = *(const float4*)&A[r * 1024 + i];
      acc.x += bb * av.x; acc.y += bb * av.y;
      acc.z += bb * av.z; acc.w += bb * av.w;
    }
    float4 wv = *(const float4*)&W[o * 1024 + i];
    uint2 ov;
    ov.x = pk_bf16(wv.x + acc.x * 0.0625f, wv.y + acc.y * 0.0625f);
    ov.y = pk_bf16(wv.z + acc.z * 0.0625f, wv.w + acc.w * 0.0625f);
    *(uint2*)&Weff[idx] = ov;
  }
}

// ============================================================
// Kernel 2: QKV GEMM. 128x128 tile, BK=64 via two 32-k half-buffers
// (64-B LDS rows -> conflict-free frag reads), global_load_lds staging.
// ============================================================
__global__ __launch_bounds__(256) void gemm_qkv(
    const unsigned short* __restrict__ X, const unsigned short* __restrict__ Weff,
    const float* __restrict__ bq, const float* __restrict__ bk, const float* __restrict__ bv,
    unsigned short* __restrict__ qbuf, unsigned short* __restrict__ kbuf,
    unsigned short* __restrict__ vtbuf) {
  __shared__ __align__(16) unsigned short As[2][128][32];
  __shared__ __align__(16) unsigned short Bs[2][128][32];
  const int K = 1024;
  int tid = threadIdx.x;
  int lane = tid & 63;
  int w = tid >> 6;
  int wm = (w >> 1) * 64;
  int wn = (w & 1) * 64;
  int c = lane & 15;
  int quad = lane >> 4;

  int bid = blockIdx.x;
  int grp = bid / 192;
  int rem = bid % 192;
  int m0 = (grp * 8 + (rem & 7)) * 128;
  int n0 = (rem >> 3) * 128;
  int p = n0 >> 10;

  // staging: 16 rows x 32 cols per gll16 (64-B LDS rows)
  int ldr = lane >> 2;          // 0..15
  int ldc = (lane & 3) * 8;     // 0..24
  const unsigned short* gA = X + (m0 + w * 32 + ldr) * K + ldc;
  const unsigned short* gB = Weff + (n0 + w * 32 + ldr) * K + ldc;

  f32x4 acc[4][4] = {};

  if (p == 2) {
    for (int k0 = 0; k0 < K; k0 += 64) {
      __syncthreads();
#pragma unroll
      for (int hh = 0; hh < 2; hh++) {
        gll16(gA + k0 + hh * 32, &As[hh][w * 32][0]);
        gll16(gA + k0 + hh * 32 + 16 * K, &As[hh][w * 32 + 16][0]);
        gll16(gB + k0 + hh * 32, &Bs[hh][w * 32][0]);
        gll16(gB + k0 + hh * 32 + 16 * K, &Bs[hh][w * 32 + 16][0]);
      }
      __syncthreads();
#pragma unroll
      for (int hh = 0; hh < 2; hh++) {
        bf16x8 af[4], bfr[4];
#pragma unroll
        for (int mi = 0; mi < 4; mi++)
          af[mi] = *(const bf16x8*)&As[hh][wm + mi * 16 + c][quad * 8];
#pragma unroll
        for (int ni = 0; ni < 4; ni++)
          bfr[ni] = *(const bf16x8*)&Bs[hh][wn + ni * 16 + c][quad * 8];
#pragma unroll
        for (int mi = 0; mi < 4; mi++)
#pragma unroll
          for (int ni = 0; ni < 4; ni++)
            acc[mi][ni] = __builtin_amdgcn_mfma_f32_16x16x32_bf16(af[mi], bfr[ni], acc[mi][ni], 0, 0, 0);
      }
    }
    const float* bias = bv;
#pragma unroll
    for (int ni = 0; ni < 4; ni++) {
      int o = (n0 + wn + ni * 16 + c) & 1023;
      int h = o >> 6;
      int d = o & 63;
      float bval = bias[o];
#pragma unroll
      for (int mi = 0; mi < 4; mi++) {
        int mbase = m0 + wm + mi * 16 + quad * 4;
        int bb = mbase >> 11;
        int s = mbase & 2047;
        uint2 o4;
        o4.x = pk_bf16(acc[mi][ni][0] + bval, acc[mi][ni][1] + bval);
        o4.y = pk_bf16(acc[mi][ni][2] + bval, acc[mi][ni][3] + bval);
        *(uint2*)&vtbuf[((bb * 16 + h) * 64 + d) * 2048 + s] = o4;
      }
    }
  } else {
    for (int k0 = 0; k0 < K; k0 += 64) {
      __syncthreads();
#pragma unroll
      for (int hh = 0; hh < 2; hh++) {
        gll16(gA + k0 + hh * 32, &As[hh][w * 32][0]);
        gll16(gA + k0 + hh * 32 + 16 * K, &As[hh][w * 32 + 16][0]);
        gll16(gB + k0 + hh * 32, &Bs[hh][w * 32][0]);
        gll16(gB + k0 + hh * 32 + 16 * K, &Bs[hh][w * 32 + 16][0]);
      }
      __syncthreads();
#pragma unroll
      for (int hh = 0; hh < 2; hh++) {
        bf16x8 af[4], bfr[4];
#pragma unroll
        for (int mi = 0; mi < 4; mi++)
          af[mi] = *(const bf16x8*)&As[hh][wm + mi * 16 + c][quad * 8];
#pragma unroll
        for (int ni = 0; ni < 4; ni++)
          bfr[ni] = *(const bf16x8*)&Bs[hh][wn + ni * 16 + c][quad * 8];
#pragma unroll
        for (int mi = 0; mi < 4; mi++)
#pragma unroll
          for (int ni = 0; ni < 4; ni++)
            acc[mi][ni] = __builtin_amdgcn_mfma_f32_16x16x32_bf16(bfr[ni], af[mi], acc[mi][ni], 0, 0, 0);
      }
    }
    const float* bias = (p == 1) ? bk : bq;
    unsigned short* dst = (p == 1) ? kbuf : qbuf;
#pragma unroll
    for (int mi = 0; mi < 4; mi++) {
      int m = m0 + wm + mi * 16 + c;
      int bb = m >> 11;
      int ss = m & 2047;
#pragma unroll
      for (int ni = 0; ni < 4; ni++) {
        int o = (n0 + wn + ni * 16 + quad * 4) & 1023;
        int h = o >> 6;
        int d = o & 63;
        float4 b4 = *(const float4*)&bias[o];
        uint2 o4;
        o4.x = pk_bf16(acc[mi][ni][0] + b4.x, acc[mi][ni][1] + b4.y);
        o4.y = pk_bf16(acc[mi][ni][2] + b4.z, acc[mi][ni][3] + b4.w);
        *(uint2*)&dst[((bb * 16 + h) * 2048 + ss) * 64 + d] = o4;
      }
    }
  }
}

// ============================================================
// Kernel 3: flash attention. TQ=256, 4 waves x 64 q, 64-key tiles.
// Double-buffered K/V LDS (1 barrier/tile), XCD-swizzled grid,
// Q frags + P in registers, masks preloaded, deferred softmax.
// T5: s_setprio(1) around MFMA clusters — 2 blocks/CU are independently
// phased, so MFMA-phase waves preempt the other block's staging/VALU.
// ============================================================
__global__ __launch_bounds__(256, 2) void attn_kernel(
    const unsigned short* __restrict__ qbuf, const unsigned short* __restrict__ kbuf,
    const unsigned short* __restrict__ vtbuf, const float* __restrict__ maskg,
    float* __restrict__ out) {
  __shared__ __align__(16) unsigned short Ks[2][64][72];
  __shared__ __align__(16) unsigned short Vts[2][64][72];   // [buf][d][key]
  __shared__ __align__(16) float masks2[2048];
  __shared__ __align__(16) float lrow[256];

  const float SC = 0.125f * 1.4426950408889634f;
  const float L2E = 1.4426950408889634f;

  int tid = threadIdx.x;
  int lane = tid & 63;
  int w = tid >> 6;
  int m31 = lane & 31;
  int hi = lane >> 5;

  // XCD swizzle: id%8 == bh%8 so all q-tiles of a bh share an XCD's L2
  int g = blockIdx.x;                    // 0..511
  int qt = (g >> 3) & 7;
  int bh = ((g >> 6) << 3) | (g & 7);
  int b = bh >> 4;
  int h = bh & 15;
  int q0 = qt * 256;

  const unsigned short* Qbh = qbuf + bh * (2048 * 64);
  const unsigned short* Kbh = kbuf + bh * (2048 * 64);
  const unsigned short* Vbh = vtbuf + bh * (64 * 2048);

#pragma unroll
  for (int i = 0; i < 2; i++) {
    int idx = (i * 256 + tid) * 4;
    float4 mm = *(const float4*)(maskg + b * 2048 + idx);
    float4 mo;
    mo.x = (mm.x - 8.f) * L2E;
    mo.y = (mm.y - 8.f) * L2E;
    mo.z = (mm.z - 8.f) * L2E;
    mo.w = (mm.w - 8.f) * L2E;
    *(float4*)&masks2[idx] = mo;
  }

  bf16x8 qfr[2][4];
#pragma unroll
  for (int qb = 0; qb < 2; qb++)
#pragma unroll
    for (int ks = 0; ks < 4; ks++)
      qfr[qb][ks] = *(const bf16x8*)(Qbh + (q0 + w * 64 + qb * 32 + m31) * 64 + ks * 16 + hi * 8);

  int r2 = tid >> 3;
  int ch = (tid & 7) * 8;

  {
    uint4 t0 = *(const uint4*)(Kbh + r2 * 64 + ch);
    uint4 t1 = *(const uint4*)(Kbh + (32 + r2) * 64 + ch);
    uint4 t2 = *(const uint4*)(Vbh + r2 * 2048 + ch);
    uint4 t3 = *(const uint4*)(Vbh + (r2 + 32) * 2048 + ch);
    *(uint4*)&Ks[0][r2][ch] = t0;
    *(uint4*)&Ks[0][r2 + 32][ch] = t1;
    *(uint4*)&Vts[0][r2][ch] = t2;
    *(uint4*)&Vts[0][r2 + 32][ch] = t3;
  }
  uint4 pkv0 = *(const uint4*)(Kbh + (64 + r2) * 64 + ch);
  uint4 pkv1 = *(const uint4*)(Kbh + (64 + 32 + r2) * 64 + ch);
  uint4 pkv2 = *(const uint4*)(Vbh + r2 * 2048 + 64 + ch);
  uint4 pkv3 = *(const uint4*)(Vbh + (r2 + 32) * 2048 + 64 + ch);

  __syncthreads();

  float lsum[2] = {0.f, 0.f};
  f32x16 acc_o[2][2] = {};

  for (int t = 0; t < 32; t++) {
    int cur = t & 1;
    int kt = t * 64;

#pragma unroll
    for (int kb = 0; kb < 2; kb++) {
      f32x16 accs[2] = {};
      __builtin_amdgcn_s_setprio(1);
#pragma unroll
      for (int ks = 0; ks < 4; ks++) {
        bf16x8 kf = *(const bf16x8*)&Ks[cur][kb * 32 + m31][ks * 16 + hi * 8];
#pragma unroll
        for (int qb = 0; qb < 2; qb++)
          accs[qb] = __builtin_amdgcn_mfma_f32_32x32x16_bf16(kf, qfr[qb][ks], accs[qb], 0, 0, 0);
      }
      __builtin_amdgcn_s_setprio(0);

      unsigned int up[2][4][2];
#pragma unroll
      for (int gg = 0; gg < 4; gg++) {
        float4 m4 = *(const float4*)&masks2[kt + kb * 32 + gg * 8 + hi * 4];
#pragma unroll
        for (int qb = 0; qb < 2; qb++) {
          float p0 = exp2_hw(fmaf(accs[qb][gg * 4 + 0], SC, m4.x));
          float p1 = exp2_hw(fmaf(accs[qb][gg * 4 + 1], SC, m4.y));
          float p2 = exp2_hw(fmaf(accs[qb][gg * 4 + 2], SC, m4.z));
          float p3 = exp2_hw(fmaf(accs[qb][gg * 4 + 3], SC, m4.w));
          lsum[qb] += (p0 + p1) + (p2 + p3);
          up[qb][gg][0] = pk_bf16(p0, p1);
          up[qb][gg][1] = pk_bf16(p2, p3);
        }
      }

#if HAS_X8
      __builtin_amdgcn_s_setprio(1);
#pragma unroll
      for (int gg = 0; gg < 4; gg++) {
        int col = kb * 32 + gg * 8 + hi * 4;
#pragma unroll
        for (int db = 0; db < 2; db++) {
          union { uint2 u; s16x4 s; } vc;
          vc.u = *(const uint2*)&Vts[cur][db * 32 + m31][col];
#pragma unroll
          for (int qb = 0; qb < 2; qb++) {
            union { uint2 u; s16x4 s; } pc;
            pc.u.x = up[qb][gg][0];
            pc.u.y = up[qb][gg][1];
            acc_o[db][qb] = __builtin_amdgcn_mfma_f32_32x32x8bf16_1k(pc.s, vc.s, acc_o[db][qb], 0, 0, 0);
          }
        }
      }
      __builtin_amdgcn_s_setprio(0);
#else
#pragma unroll
      for (int gp = 0; gp < 2; gp++) {
        union { uint4 u; bf16x8 bv8; } pf[2];
#pragma unroll
        for (int qb = 0; qb < 2; qb++) {
          unsigned int A0 = up[qb][gp * 2][0], A1 = up[qb][gp * 2][1];
          unsigned int B0 = up[qb][gp * 2 + 1][0], B1 = up[qb][gp * 2 + 1][1];
          unsigned int A0x = (unsigned int)__shfl_xor((int)A0, 32);
          unsigned int A1x = (unsigned int)__shfl_xor((int)A1, 32);
          unsigned int B0x = (unsigned int)__shfl_xor((int)B0, 32);
          unsigned int B1x = (unsigned int)__shfl_xor((int)B1, 32);
          pf[qb].u.x = hi ? B0x : A0;
          pf[qb].u.y = hi ? B1x : A1;
          pf[qb].u.z = hi ? B0 : A0x;
          pf[qb].u.w = hi ? B1 : A1x;
        }
        __builtin_amdgcn_s_setprio(1);
#pragma unroll
        for (int db = 0; db < 2; db++) {
          bf16x8 vf = *(const bf16x8*)&Vts[cur][db * 32 + m31][kb * 32 + gp * 16 + hi * 8];
#pragma unroll
          for (int qb = 0; qb < 2; qb++)
            acc_o[db][qb] = __builtin_amdgcn_mfma_f32_32x32x16_bf16(pf[qb].bv8, vf, acc_o[db][qb], 0, 0, 0);
        }
        __builtin_amdgcn_s_setprio(0);
      }
#endif
    }

    if (t < 31) {
      int nb = cur ^ 1;
      *(uint4*)&Ks[nb][r2][ch] = pkv0;
      *(uint4*)&Ks[nb][r2 + 32][ch] = pkv1;
      *(uint4*)&Vts[nb][r2][ch] = pkv2;
      *(uint4*)&Vts[nb][r2 + 32][ch] = pkv3;
      int kn = (kt + 128) & 2047;
      pkv0 = *(const uint4*)(Kbh + (kn + r2) * 64 + ch);
      pkv1 = *(const uint4*)(Kbh + (kn + 32 + r2) * 64 + ch);
      pkv2 = *(const uint4*)(Vbh + r2 * 2048 + kn + ch);
      pkv3 = *(const uint4*)(Vbh + (r2 + 32) * 2048 + kn + ch);
    }
    __syncthreads();
  }

#pragma unroll
  for (int qb = 0; qb < 2; qb++) {
    lsum[qb] += __shfl_xor(lsum[qb], 32);
    lrow[w * 64 + qb * 32 + m31] = lsum[qb];
  }
  __asm__ volatile("" ::: "memory");

#pragma unroll
  for (int qb = 0; qb < 2; qb++)
#pragma unroll
    for (int gg = 0; gg < 4; gg++) {
      float4 l4 = *(const float4*)&lrow[w * 64 + qb * 32 + gg * 8 + hi * 4];
      float i0 = rcp_hw(l4.x), i1 = rcp_hw(l4.y), i2 = rcp_hw(l4.z), i3 = rcp_hw(l4.w);
      int qq = q0 + w * 64 + qb * 32 + gg * 8 + hi * 4;
#pragma unroll
      for (int db = 0; db < 2; db++) {
        float* obase = out + (b * 2048 + qq) * 1024 + h * 64 + db * 32 + m31;
        obase[0 * 1024] = acc_o[db][qb][gg * 4 + 0] * i0;
        obase[1 * 1024] = acc_o[db][qb][gg * 4 + 1] * i1;
        obase[2 * 1024] = acc_o[db][qb][gg * 4 + 2] * i2;
        obase[3 * 1024] = acc_o[db][qb][gg * 4 + 3] * i3;
      }
    }
}

// ============================================================
extern "C" void kernel_launch(void* const* d_in, const int* in_sizes, int n_in,
                              void* d_out, int out_size, void* d_ws, size_t ws_size,
                              hipStream_t stream) {
  const float* X    = (const float*)d_in[0];
  const float* mask = (const float*)d_in[1];
  const float* Wq = (const float*)d_in[2];
  const float* bq = (const float*)d_in[3];
  const float* Aq = (const float*)d_in[4];
  const float* Bq = (const float*)d_in[5];
  const float* Wk = (const float*)d_in[6];
  const float* bk = (const float*)d_in[7];
  const float* Ak = (const float*)d_in[8];
  const float* Bk = (const float*)d_in[9];
  const float* Wv = (const float*)d_in[10];
  const float* bv = (const float*)d_in[11];
  const float* Av = (const float*)d_in[12];
  const float* Bv = (const float*)d_in[13];

  unsigned short* ws    = (unsigned short*)d_ws;
  unsigned short* Xbf   = ws;
  unsigned short* Weff  = Xbf + 8388608;
  unsigned short* qbuf  = Weff + 3145728;
  unsigned short* kbuf  = qbuf + 8388608;
  unsigned short* vtbuf = kbuf + 8388608;

  prep_kernel<<<dim3(11264), dim3(256), 0, stream>>>(X, Xbf, Wq, Aq, Bq, Wk, Ak, Bk, Wv, Av, Bv, Weff);
  gemm_qkv<<<dim3(1536), dim3(256), 0, stream>>>(Xbf, Weff, bq, bk, bv, qbuf, kbuf, vtbuf);
  attn_kernel<<<dim3(512), dim3(256), 0, stream>>>(qbuf, kbuf, vtbuf, mask, (float*)d_out);
}

// Round 3
// 263.273 us; speedup vs baseline: 1.0212x; 1.0212x over previous
//
#include <hip/hip_runtime.h>
#include <stdint.h>

typedef __bf16 bf16x8 __attribute__((ext_vector_type(8)));
typedef float f32x4 __attribute__((ext_vector_type(4)));
typedef float f32x16 __attribute__((ext_vector_type(16)));

static __device__ __forceinline__ unsigned int pk_bf16(float a, float b) {
  unsigned int d;
  asm("v_cvt_pk_bf16_f32 %0, %1, %2" : "=v"(d) : "v"(a), "v"(b));
  return d;
}
static __device__ __forceinline__ float exp2_hw(float x) {
  float r;
  asm("v_exp_f32 %0, %1" : "=v"(r) : "v"(x));
  return r;
}
static __device__ __forceinline__ float rcp_hw(float x) {
  float r;
  asm("v_rcp_f32 %0, %1" : "=v"(r) : "v"(x));
  return r;
}
static __device__ __forceinline__ void gll16(const void* g, void* l) {
  __builtin_amdgcn_global_load_lds((const __attribute__((address_space(1))) unsigned int*)g,
                                   (__attribute__((address_space(3))) unsigned int*)l,
                                   16, 0, 0);
}

// ============================================================
// Kernel 0: fused prep.  blocks [0,8192): X f32 -> bf16 (4/thread)
//           blocks [8192,11264): W_eff = W + (1/16) B@A (4/thread)
// ============================================================
__global__ __launch_bounds__(256) void prep_kernel(
    const float* __restrict__ X, unsigned short* __restrict__ Xbf,
    const float* __restrict__ Wq, const float* __restrict__ Aq, const float* __restrict__ Bq,
    const float* __restrict__ Wk, const float* __restrict__ Ak, const float* __restrict__ Bk,
    const float* __restrict__ Wv, const float* __restrict__ Av, const float* __restrict__ Bv,
    unsigned short* __restrict__ Weff) {
  int bid = blockIdx.x;
  if (bid < 8192) {
    int i = (bid * 256 + threadIdx.x) * 4;
    float4 v = *(const float4*)(X + i);
    uint2 o;
    o.x = pk_bf16(v.x, v.y);
    o.y = pk_bf16(v.z, v.w);
    *(uint2*)(Xbf + i) = o;
  } else {
    int idx = ((bid - 8192) * 256 + threadIdx.x) * 4;
    int p = idx >> 20;
    int o = (idx >> 10) & 1023;
    int i = idx & 1023;
    const float* W = (p == 0) ? Wq : (p == 1) ? Wk : Wv;
    const float* A = (p == 0) ? Aq : (p == 1) ? Ak : Av;
    const float* B = (p == 0) ? Bq : (p == 1) ? Bk : Bv;
    float4 acc = {0.f, 0.f, 0.f, 0.f};
#pragma unroll
    for (int r = 0; r < 16; ++r) {
      float bb = B[o * 16 + r];
      float4 av = *(const float4*)&A[r * 1024 + i];
      acc.x += bb * av.x; acc.y += bb * av.y;
      acc.z += bb * av.z; acc.w += bb * av.w;
    }
    float4 wv = *(const float4*)&W[o * 1024 + i];
    uint2 ov;
    ov.x = pk_bf16(wv.x + acc.x * 0.0625f, wv.y + acc.y * 0.0625f);
    ov.y = pk_bf16(wv.z + acc.z * 0.0625f, wv.w + acc.w * 0.0625f);
    *(uint2*)&Weff[idx] = ov;
  }
}

// ============================================================
// Kernel 2: QKV GEMM. 128x128 tile, BK=64 via two 32-k half-buffers
// (64-B LDS rows -> conflict-free frag reads), global_load_lds staging.
// XCD swizzle: bid%8 -> XCD gets one contiguous m-group (A 2MB resident
// in its L2 across the n sweep; B panel 256KB per step).
// ============================================================
__global__ __launch_bounds__(256) void gemm_qkv(
    const unsigned short* __restrict__ X, const unsigned short* __restrict__ Weff,
    const float* __restrict__ bq, const float* __restrict__ bk, const float* __restrict__ bv,
    unsigned short* __restrict__ qbuf, unsigned short* __restrict__ kbuf,
    unsigned short* __restrict__ vtbuf) {
  __shared__ __align__(16) unsigned short As[2][128][32];
  __shared__ __align__(16) unsigned short Bs[2][128][32];
  const int K = 1024;
  int tid = threadIdx.x;
  int lane = tid & 63;
  int w = tid >> 6;
  int wm = (w >> 1) * 64;
  int wn = (w & 1) * 64;
  int c = lane & 15;
  int quad = lane >> 4;

  int bid0 = blockIdx.x;
  int bid = (bid0 & 7) * 192 + (bid0 >> 3);   // bijective XCD swizzle (1536 % 8 == 0)
  int grp = bid / 192;
  int rem = bid % 192;
  int m0 = (grp * 8 + (rem & 7)) * 128;
  int n0 = (rem >> 3) * 128;
  int p = n0 >> 10;

  // staging: 16 rows x 32 cols per gll16 (64-B LDS rows)
  int ldr = lane >> 2;          // 0..15
  int ldc = (lane & 3) * 8;     // 0..24
  const unsigned short* gA = X + (m0 + w * 32 + ldr) * K + ldc;
  const unsigned short* gB = Weff + (n0 + w * 32 + ldr) * K + ldc;

  f32x4 acc[4][4] = {};

  if (p == 2) {
    for (int k0 = 0; k0 < K; k0 += 64) {
      __syncthreads();
#pragma unroll
      for (int hh = 0; hh < 2; hh++) {
        gll16(gA + k0 + hh * 32, &As[hh][w * 32][0]);
        gll16(gA + k0 + hh * 32 + 16 * K, &As[hh][w * 32 + 16][0]);
        gll16(gB + k0 + hh * 32, &Bs[hh][w * 32][0]);
        gll16(gB + k0 + hh * 32 + 16 * K, &Bs[hh][w * 32 + 16][0]);
      }
      __syncthreads();
#pragma unroll
      for (int hh = 0; hh < 2; hh++) {
        bf16x8 af[4], bfr[4];
#pragma unroll
        for (int mi = 0; mi < 4; mi++)
          af[mi] = *(const bf16x8*)&As[hh][wm + mi * 16 + c][quad * 8];
#pragma unroll
        for (int ni = 0; ni < 4; ni++)
          bfr[ni] = *(const bf16x8*)&Bs[hh][wn + ni * 16 + c][quad * 8];
#pragma unroll
        for (int mi = 0; mi < 4; mi++)
#pragma unroll
          for (int ni = 0; ni < 4; ni++)
            acc[mi][ni] = __builtin_amdgcn_mfma_f32_16x16x32_bf16(af[mi], bfr[ni], acc[mi][ni], 0, 0, 0);
      }
    }
    const float* bias = bv;
#pragma unroll
    for (int ni = 0; ni < 4; ni++) {
      int o = (n0 + wn + ni * 16 + c) & 1023;
      int h = o >> 6;
      int d = o & 63;
      float bval = bias[o];
#pragma unroll
      for (int mi = 0; mi < 4; mi++) {
        int mbase = m0 + wm + mi * 16 + quad * 4;
        int bb = mbase >> 11;
        int s = mbase & 2047;
        uint2 o4;
        o4.x = pk_bf16(acc[mi][ni][0] + bval, acc[mi][ni][1] + bval);
        o4.y = pk_bf16(acc[mi][ni][2] + bval, acc[mi][ni][3] + bval);
        *(uint2*)&vtbuf[((bb * 16 + h) * 64 + d) * 2048 + s] = o4;
      }
    }
  } else {
    for (int k0 = 0; k0 < K; k0 += 64) {
      __syncthreads();
#pragma unroll
      for (int hh = 0; hh < 2; hh++) {
        gll16(gA + k0 + hh * 32, &As[hh][w * 32][0]);
        gll16(gA + k0 + hh * 32 + 16 * K, &As[hh][w * 32 + 16][0]);
        gll16(gB + k0 + hh * 32, &Bs[hh][w * 32][0]);
        gll16(gB + k0 + hh * 32 + 16 * K, &Bs[hh][w * 32 + 16][0]);
      }
      __syncthreads();
#pragma unroll
      for (int hh = 0; hh < 2; hh++) {
        bf16x8 af[4], bfr[4];
#pragma unroll
        for (int mi = 0; mi < 4; mi++)
          af[mi] = *(const bf16x8*)&As[hh][wm + mi * 16 + c][quad * 8];
#pragma unroll
        for (int ni = 0; ni < 4; ni++)
          bfr[ni] = *(const bf16x8*)&Bs[hh][wn + ni * 16 + c][quad * 8];
#pragma unroll
        for (int mi = 0; mi < 4; mi++)
#pragma unroll
          for (int ni = 0; ni < 4; ni++)
            acc[mi][ni] = __builtin_amdgcn_mfma_f32_16x16x32_bf16(bfr[ni], af[mi], acc[mi][ni], 0, 0, 0);
      }
    }
    const float* bias = (p == 1) ? bk : bq;
    unsigned short* dst = (p == 1) ? kbuf : qbuf;
#pragma unroll
    for (int mi = 0; mi < 4; mi++) {
      int m = m0 + wm + mi * 16 + c;
      int bb = m >> 11;
      int ss = m & 2047;
#pragma unroll
      for (int ni = 0; ni < 4; ni++) {
        int o = (n0 + wn + ni * 16 + quad * 4) & 1023;
        int h = o >> 6;
        int d = o & 63;
        float4 b4 = *(const float4*)&bias[o];
        uint2 o4;
        o4.x = pk_bf16(acc[mi][ni][0] + b4.x, acc[mi][ni][1] + b4.y);
        o4.y = pk_bf16(acc[mi][ni][2] + b4.z, acc[mi][ni][3] + b4.w);
        *(uint2*)&dst[((bb * 16 + h) * 2048 + ss) * 64 + d] = o4;
      }
    }
  }
}

// ============================================================
// Kernel 3: flash attention. TQ=256, 4 waves x 64 q, 64-key tiles.
// Double-buffered K/V LDS (1 barrier/tile), XCD-swizzled grid,
// Q frags + P in registers, masks preloaded, deferred softmax.
// PV now uses 32x32x16 MFMA (half the issue slots of the old K=8 path):
// v_permlane32_swap_b32 builds each x16 P-fragment — one swap yields
// BOTH the lo-half (new vdst) and hi-half (new vsrc) fragment words.
// ============================================================
__global__ __launch_bounds__(256, 2) void attn_kernel(
    const unsigned short* __restrict__ qbuf, const unsigned short* __restrict__ kbuf,
    const unsigned short* __restrict__ vtbuf, const float* __restrict__ maskg,
    float* __restrict__ out) {
  __shared__ __align__(16) unsigned short Ks[2][64][72];
  __shared__ __align__(16) unsigned short Vts[2][64][72];   // [buf][d][key]
  __shared__ __align__(16) float masks2[2048];
  __shared__ __align__(16) float lrow[256];

  const float SC = 0.125f * 1.4426950408889634f;
  const float L2E = 1.4426950408889634f;

  int tid = threadIdx.x;
  int lane = tid & 63;
  int w = tid >> 6;
  int m31 = lane & 31;
  int hi = lane >> 5;

  // XCD swizzle: id%8 == bh%8 so all q-tiles of a bh share an XCD's L2
  int g = blockIdx.x;                    // 0..511
  int qt = (g >> 3) & 7;
  int bh = ((g >> 6) << 3) | (g & 7);
  int b = bh >> 4;
  int h = bh & 15;
  int q0 = qt * 256;

  const unsigned short* Qbh = qbuf + bh * (2048 * 64);
  const unsigned short* Kbh = kbuf + bh * (2048 * 64);
  const unsigned short* Vbh = vtbuf + bh * (64 * 2048);

#pragma unroll
  for (int i = 0; i < 2; i++) {
    int idx = (i * 256 + tid) * 4;
    float4 mm = *(const float4*)(maskg + b * 2048 + idx);
    float4 mo;
    mo.x = (mm.x - 8.f) * L2E;
    mo.y = (mm.y - 8.f) * L2E;
    mo.z = (mm.z - 8.f) * L2E;
    mo.w = (mm.w - 8.f) * L2E;
    *(float4*)&masks2[idx] = mo;
  }

  bf16x8 qfr[2][4];
#pragma unroll
  for (int qb = 0; qb < 2; qb++)
#pragma unroll
    for (int ks = 0; ks < 4; ks++)
      qfr[qb][ks] = *(const bf16x8*)(Qbh + (q0 + w * 64 + qb * 32 + m31) * 64 + ks * 16 + hi * 8);

  int r2 = tid >> 3;
  int ch = (tid & 7) * 8;

  {
    uint4 t0 = *(const uint4*)(Kbh + r2 * 64 + ch);
    uint4 t1 = *(const uint4*)(Kbh + (32 + r2) * 64 + ch);
    uint4 t2 = *(const uint4*)(Vbh + r2 * 2048 + ch);
    uint4 t3 = *(const uint4*)(Vbh + (r2 + 32) * 2048 + ch);
    *(uint4*)&Ks[0][r2][ch] = t0;
    *(uint4*)&Ks[0][r2 + 32][ch] = t1;
    *(uint4*)&Vts[0][r2][ch] = t2;
    *(uint4*)&Vts[0][r2 + 32][ch] = t3;
  }
  uint4 pkv0 = *(const uint4*)(Kbh + (64 + r2) * 64 + ch);
  uint4 pkv1 = *(const uint4*)(Kbh + (64 + 32 + r2) * 64 + ch);
  uint4 pkv2 = *(const uint4*)(Vbh + r2 * 2048 + 64 + ch);
  uint4 pkv3 = *(const uint4*)(Vbh + (r2 + 32) * 2048 + 64 + ch);

  __syncthreads();

  float lsum[2] = {0.f, 0.f};
  f32x16 acc_o[2][2] = {};

  for (int t = 0; t < 32; t++) {
    int cur = t & 1;
    int kt = t * 64;

#pragma unroll
    for (int kb = 0; kb < 2; kb++) {
      f32x16 accs[2] = {};
      __builtin_amdgcn_s_setprio(1);
#pragma unroll
      for (int ks = 0; ks < 4; ks++) {
        bf16x8 kf = *(const bf16x8*)&Ks[cur][kb * 32 + m31][ks * 16 + hi * 8];
#pragma unroll
        for (int qb = 0; qb < 2; qb++)
          accs[qb] = __builtin_amdgcn_mfma_f32_32x32x16_bf16(kf, qfr[qb][ks], accs[qb], 0, 0, 0);
      }
      __builtin_amdgcn_s_setprio(0);

      unsigned int up[2][4][2];
#pragma unroll
      for (int gg = 0; gg < 4; gg++) {
        float4 m4 = *(const float4*)&masks2[kt + kb * 32 + gg * 8 + hi * 4];
#pragma unroll
        for (int qb = 0; qb < 2; qb++) {
          float p0 = exp2_hw(fmaf(accs[qb][gg * 4 + 0], SC, m4.x));
          float p1 = exp2_hw(fmaf(accs[qb][gg * 4 + 1], SC, m4.y));
          float p2 = exp2_hw(fmaf(accs[qb][gg * 4 + 2], SC, m4.z));
          float p3 = exp2_hw(fmaf(accs[qb][gg * 4 + 3], SC, m4.w));
          lsum[qb] += (p0 + p1) + (p2 + p3);
          up[qb][gg][0] = pk_bf16(p0, p1);
          up[qb][gg][1] = pk_bf16(p2, p3);
        }
      }

      // PV with K=16 MFMA: build x16 P-fragments via permlane32_swap.
      // new_vdst = lo?A:B_from_lo  (frag words 0,1)
      // new_vsrc = lo?A_from_hi:B  (frag words 2,3)
#pragma unroll
      for (int gp = 0; gp < 2; gp++) {
        union { uint4 u; bf16x8 bv8; } pf[2];
#pragma unroll
        for (int qb = 0; qb < 2; qb++) {
          unsigned int a0 = up[qb][gp * 2][0], b0 = up[qb][gp * 2 + 1][0];
          unsigned int a1 = up[qb][gp * 2][1], b1 = up[qb][gp * 2 + 1][1];
          asm("v_permlane32_swap_b32 %0, %1" : "+v"(a0), "+v"(b0));
          asm("v_permlane32_swap_b32 %0, %1" : "+v"(a1), "+v"(b1));
          pf[qb].u.x = a0;
          pf[qb].u.y = a1;
          pf[qb].u.z = b0;
          pf[qb].u.w = b1;
        }
        __builtin_amdgcn_s_setprio(1);
#pragma unroll
        for (int db = 0; db < 2; db++) {
          bf16x8 vf = *(const bf16x8*)&Vts[cur][db * 32 + m31][kb * 32 + gp * 16 + hi * 8];
#pragma unroll
          for (int qb = 0; qb < 2; qb++)
            acc_o[db][qb] = __builtin_amdgcn_mfma_f32_32x32x16_bf16(pf[qb].bv8, vf, acc_o[db][qb], 0, 0, 0);
        }
        __builtin_amdgcn_s_setprio(0);
      }
    }

    if (t < 31) {
      int nb = cur ^ 1;
      *(uint4*)&Ks[nb][r2][ch] = pkv0;
      *(uint4*)&Ks[nb][r2 + 32][ch] = pkv1;
      *(uint4*)&Vts[nb][r2][ch] = pkv2;
      *(uint4*)&Vts[nb][r2 + 32][ch] = pkv3;
      int kn = (kt + 128) & 2047;
      pkv0 = *(const uint4*)(Kbh + (kn + r2) * 64 + ch);
      pkv1 = *(const uint4*)(Kbh + (kn + 32 + r2) * 64 + ch);
      pkv2 = *(const uint4*)(Vbh + r2 * 2048 + kn + ch);
      pkv3 = *(const uint4*)(Vbh + (r2 + 32) * 2048 + kn + ch);
    }
    __syncthreads();
  }

#pragma unroll
  for (int qb = 0; qb < 2; qb++) {
    lsum[qb] += __shfl_xor(lsum[qb], 32);
    lrow[w * 64 + qb * 32 + m31] = lsum[qb];
  }
  __asm__ volatile("" ::: "memory");

#pragma unroll
  for (int qb = 0; qb < 2; qb++)
#pragma unroll
    for (int gg = 0; gg < 4; gg++) {
      float4 l4 = *(const float4*)&lrow[w * 64 + qb * 32 + gg * 8 + hi * 4];
      float i0 = rcp_hw(l4.x), i1 = rcp_hw(l4.y), i2 = rcp_hw(l4.z), i3 = rcp_hw(l4.w);
      int qq = q0 + w * 64 + qb * 32 + gg * 8 + hi * 4;
#pragma unroll
      for (int db = 0; db < 2; db++) {
        float* obase = out + (b * 2048 + qq) * 1024 + h * 64 + db * 32 + m31;
        obase[0 * 1024] = acc_o[db][qb][gg * 4 + 0] * i0;
        obase[1 * 1024] = acc_o[db][qb][gg * 4 + 1] * i1;
        obase[2 * 1024] = acc_o[db][qb][gg * 4 + 2] * i2;
        obase[3 * 1024] = acc_o[db][qb][gg * 4 + 3] * i3;
      }
    }
}

// ============================================================
extern "C" void kernel_launch(void* const* d_in, const int* in_sizes, int n_in,
                              void* d_out, int out_size, void* d_ws, size_t ws_size,
                              hipStream_t stream) {
  const float* X    = (const float*)d_in[0];
  const float* mask = (const float*)d_in[1];
  const float* Wq = (const float*)d_in[2];
  const float* bq = (const float*)d_in[3];
  const float* Aq = (const float*)d_in[4];
  const float* Bq = (const float*)d_in[5];
  const float* Wk = (const float*)d_in[6];
  const float* bk = (const float*)d_in[7];
  const float* Ak = (const float*)d_in[8];
  const float* Bk = (const float*)d_in[9];
  const float* Wv = (const float*)d_in[10];
  const float* bv = (const float*)d_in[11];
  const float* Av = (const float*)d_in[12];
  const float* Bv = (const float*)d_in[13];

  unsigned short* ws    = (unsigned short*)d_ws;
  unsigned short* Xbf   = ws;
  unsigned short* Weff  = Xbf + 8388608;
  unsigned short* qbuf  = Weff + 3145728;
  unsigned short* kbuf  = qbuf + 8388608;
  unsigned short* vtbuf = kbuf + 8388608;

  prep_kernel<<<dim3(11264), dim3(256), 0, stream>>>(X, Xbf, Wq, Aq, Bq, Wk, Ak, Bk, Wv, Av, Bv, Weff);
  gemm_qkv<<<dim3(1536), dim3(256), 0, stream>>>(Xbf, Weff, bq, bk, bv, qbuf, kbuf, vtbuf);
  attn_kernel<<<dim3(512), dim3(256), 0, stream>>>(qbuf, kbuf, vtbuf, mask, (float*)d_out);
}

// Round 4
// 258.486 us; speedup vs baseline: 1.0401x; 1.0185x over previous
//
#include <hip/hip_runtime.h>
#include <stdint.h>

typedef __bf16 bf16x8 __attribute__((ext_vector_type(8)));
typedef float f32x4 __attribute__((ext_vector_type(4)));
typedef float f32x16 __attribute__((ext_vector_type(16)));

static __device__ __forceinline__ unsigned int pk_bf16(float a, float b) {
  unsigned int d;
  asm("v_cvt_pk_bf16_f32 %0, %1, %2" : "=v"(d) : "v"(a), "v"(b));
  return d;
}
static __device__ __forceinline__ float exp2_hw(float x) {
  float r;
  asm("v_exp_f32 %0, %1" : "=v"(r) : "v"(x));
  return r;
}
static __device__ __forceinline__ float rcp_hw(float x) {
  float r;
  asm("v_rcp_f32 %0, %1" : "=v"(r) : "v"(x));
  return r;
}
static __device__ __forceinline__ void gll16(const void* g, void* l) {
  __builtin_amdgcn_global_load_lds((const __attribute__((address_space(1))) unsigned int*)g,
                                   (__attribute__((address_space(3))) unsigned int*)l,
                                   16, 0, 0);
}

// ============================================================
// Kernel 0: fused prep.  blocks [0,8192): X f32 -> bf16 (4/thread)
//           blocks [8192,11264): W_eff = W + (1/16) B@A (4/thread)
// ============================================================
__global__ __launch_bounds__(256) void prep_kernel(
    const float* __restrict__ X, unsigned short* __restrict__ Xbf,
    const float* __restrict__ Wq, const float* __restrict__ Aq, const float* __restrict__ Bq,
    const float* __restrict__ Wk, const float* __restrict__ Ak, const float* __restrict__ Bk,
    const float* __restrict__ Wv, const float* __restrict__ Av, const float* __restrict__ Bv,
    unsigned short* __restrict__ Weff) {
  int bid = blockIdx.x;
  if (bid < 8192) {
    int i = (bid * 256 + threadIdx.x) * 4;
    float4 v = *(const float4*)(X + i);
    uint2 o;
    o.x = pk_bf16(v.x, v.y);
    o.y = pk_bf16(v.z, v.w);
    *(uint2*)(Xbf + i) = o;
  } else {
    int idx = ((bid - 8192) * 256 + threadIdx.x) * 4;
    int p = idx >> 20;
    int o = (idx >> 10) & 1023;
    int i = idx & 1023;
    const float* W = (p == 0) ? Wq : (p == 1) ? Wk : Wv;
    const float* A = (p == 0) ? Aq : (p == 1) ? Ak : Av;
    const float* B = (p == 0) ? Bq : (p == 1) ? Bk : Bv;
    float4 acc = {0.f, 0.f, 0.f, 0.f};
#pragma unroll
    for (int r = 0; r < 16; ++r) {
      float bb = B[o * 16 + r];
      float4 av = *(const float4*)&A[r * 1024 + i];
      acc.x += bb * av.x; acc.y += bb * av.y;
      acc.z += bb * av.z; acc.w += bb * av.w;
    }
    float4 wv = *(const float4*)&W[o * 1024 + i];
    uint2 ov;
    ov.x = pk_bf16(wv.x + acc.x * 0.0625f, wv.y + acc.y * 0.0625f);
    ov.y = pk_bf16(wv.z + acc.z * 0.0625f, wv.w + acc.w * 0.0625f);
    *(uint2*)&Weff[idx] = ov;
  }
}

// ============================================================
// Kernel 2: QKV GEMM. 128x128 tile, BK=64 via two 32-k half-buffers
// (64-B LDS rows -> conflict-free frag reads), global_load_lds staging.
// (XCD swizzle reverted: R3 showed +6us on non-attn segment — the
// default order already shares one 256KB B-panel across XCDs.)
// ============================================================
__global__ __launch_bounds__(256) void gemm_qkv(
    const unsigned short* __restrict__ X, const unsigned short* __restrict__ Weff,
    const float* __restrict__ bq, const float* __restrict__ bk, const float* __restrict__ bv,
    unsigned short* __restrict__ qbuf, unsigned short* __restrict__ kbuf,
    unsigned short* __restrict__ vtbuf) {
  __shared__ __align__(16) unsigned short As[2][128][32];
  __shared__ __align__(16) unsigned short Bs[2][128][32];
  const int K = 1024;
  int tid = threadIdx.x;
  int lane = tid & 63;
  int w = tid >> 6;
  int wm = (w >> 1) * 64;
  int wn = (w & 1) * 64;
  int c = lane & 15;
  int quad = lane >> 4;

  int bid = blockIdx.x;
  int grp = bid / 192;
  int rem = bid % 192;
  int m0 = (grp * 8 + (rem & 7)) * 128;
  int n0 = (rem >> 3) * 128;
  int p = n0 >> 10;

  // staging: 16 rows x 32 cols per gll16 (64-B LDS rows)
  int ldr = lane >> 2;          // 0..15
  int ldc = (lane & 3) * 8;     // 0..24
  const unsigned short* gA = X + (m0 + w * 32 + ldr) * K + ldc;
  const unsigned short* gB = Weff + (n0 + w * 32 + ldr) * K + ldc;

  f32x4 acc[4][4] = {};

  if (p == 2) {
    for (int k0 = 0; k0 < K; k0 += 64) {
      __syncthreads();
#pragma unroll
      for (int hh = 0; hh < 2; hh++) {
        gll16(gA + k0 + hh * 32, &As[hh][w * 32][0]);
        gll16(gA + k0 + hh * 32 + 16 * K, &As[hh][w * 32 + 16][0]);
        gll16(gB + k0 + hh * 32, &Bs[hh][w * 32][0]);
        gll16(gB + k0 + hh * 32 + 16 * K, &Bs[hh][w * 32 + 16][0]);
      }
      __syncthreads();
#pragma unroll
      for (int hh = 0; hh < 2; hh++) {
        bf16x8 af[4], bfr[4];
#pragma unroll
        for (int mi = 0; mi < 4; mi++)
          af[mi] = *(const bf16x8*)&As[hh][wm + mi * 16 + c][quad * 8];
#pragma unroll
        for (int ni = 0; ni < 4; ni++)
          bfr[ni] = *(const bf16x8*)&Bs[hh][wn + ni * 16 + c][quad * 8];
#pragma unroll
        for (int mi = 0; mi < 4; mi++)
#pragma unroll
          for (int ni = 0; ni < 4; ni++)
            acc[mi][ni] = __builtin_amdgcn_mfma_f32_16x16x32_bf16(af[mi], bfr[ni], acc[mi][ni], 0, 0, 0);
      }
    }
    const float* bias = bv;
#pragma unroll
    for (int ni = 0; ni < 4; ni++) {
      int o = (n0 + wn + ni * 16 + c) & 1023;
      int h = o >> 6;
      int d = o & 63;
      float bval = bias[o];
#pragma unroll
      for (int mi = 0; mi < 4; mi++) {
        int mbase = m0 + wm + mi * 16 + quad * 4;
        int bb = mbase >> 11;
        int s = mbase & 2047;
        uint2 o4;
        o4.x = pk_bf16(acc[mi][ni][0] + bval, acc[mi][ni][1] + bval);
        o4.y = pk_bf16(acc[mi][ni][2] + bval, acc[mi][ni][3] + bval);
        *(uint2*)&vtbuf[((bb * 16 + h) * 64 + d) * 2048 + s] = o4;
      }
    }
  } else {
    for (int k0 = 0; k0 < K; k0 += 64) {
      __syncthreads();
#pragma unroll
      for (int hh = 0; hh < 2; hh++) {
        gll16(gA + k0 + hh * 32, &As[hh][w * 32][0]);
        gll16(gA + k0 + hh * 32 + 16 * K, &As[hh][w * 32 + 16][0]);
        gll16(gB + k0 + hh * 32, &Bs[hh][w * 32][0]);
        gll16(gB + k0 + hh * 32 + 16 * K, &Bs[hh][w * 32 + 16][0]);
      }
      __syncthreads();
#pragma unroll
      for (int hh = 0; hh < 2; hh++) {
        bf16x8 af[4], bfr[4];
#pragma unroll
        for (int mi = 0; mi < 4; mi++)
          af[mi] = *(const bf16x8*)&As[hh][wm + mi * 16 + c][quad * 8];
#pragma unroll
        for (int ni = 0; ni < 4; ni++)
          bfr[ni] = *(const bf16x8*)&Bs[hh][wn + ni * 16 + c][quad * 8];
#pragma unroll
        for (int mi = 0; mi < 4; mi++)
#pragma unroll
          for (int ni = 0; ni < 4; ni++)
            acc[mi][ni] = __builtin_amdgcn_mfma_f32_16x16x32_bf16(bfr[ni], af[mi], acc[mi][ni], 0, 0, 0);
      }
    }
    const float* bias = (p == 1) ? bk : bq;
    unsigned short* dst = (p == 1) ? kbuf : qbuf;
#pragma unroll
    for (int mi = 0; mi < 4; mi++) {
      int m = m0 + wm + mi * 16 + c;
      int bb = m >> 11;
      int ss = m & 2047;
#pragma unroll
      for (int ni = 0; ni < 4; ni++) {
        int o = (n0 + wn + ni * 16 + quad * 4) & 1023;
        int h = o >> 6;
        int d = o & 63;
        float4 b4 = *(const float4*)&bias[o];
        uint2 o4;
        o4.x = pk_bf16(acc[mi][ni][0] + b4.x, acc[mi][ni][1] + b4.y);
        o4.y = pk_bf16(acc[mi][ni][2] + b4.z, acc[mi][ni][3] + b4.w);
        *(uint2*)&dst[((bb * 16 + h) * 2048 + ss) * 64 + d] = o4;
      }
    }
  }
}

// ============================================================
// Kernel 3: flash attention. TQ=256 per block, now 8 waves x 32 q
// (512 threads) -> 4 waves/SIMD (was 2): R3 counters showed
// latency-bound (Occ 17.8%, Mfma 33 + VALU 44, HBM 8%). Same LDS,
// same 1-barrier/tile double buffer, same traffic; per-wave state
// halves so 4 waves/SIMD fit (launch_bounds cap 128 VGPR).
// PV uses 32x32x16 MFMA with permlane32_swap P-fragments (verified R3).
// ============================================================
__global__ __launch_bounds__(512, 4) void attn_kernel(
    const unsigned short* __restrict__ qbuf, const unsigned short* __restrict__ kbuf,
    const unsigned short* __restrict__ vtbuf, const float* __restrict__ maskg,
    float* __restrict__ out) {
  __shared__ __align__(16) unsigned short Ks[2][64][72];
  __shared__ __align__(16) unsigned short Vts[2][64][72];   // [buf][d][key]
  __shared__ __align__(16) float masks2[2048];
  __shared__ __align__(16) float lrow[256];

  const float SC = 0.125f * 1.4426950408889634f;
  const float L2E = 1.4426950408889634f;

  int tid = threadIdx.x;
  int lane = tid & 63;
  int w = tid >> 6;              // 0..7, each wave owns 32 q rows
  int m31 = lane & 31;
  int hi = lane >> 5;

  // XCD swizzle: id%8 == bh%8 so all q-tiles of a bh share an XCD's L2
  int g = blockIdx.x;                    // 0..511
  int qt = (g >> 3) & 7;
  int bh = ((g >> 6) << 3) | (g & 7);
  int b = bh >> 4;
  int h = bh & 15;
  int q0 = qt * 256;

  const unsigned short* Qbh = qbuf + bh * (2048 * 64);
  const unsigned short* Kbh = kbuf + bh * (2048 * 64);
  const unsigned short* Vbh = vtbuf + bh * (64 * 2048);

  {
    int idx = tid * 4;
    float4 mm = *(const float4*)(maskg + b * 2048 + idx);
    float4 mo;
    mo.x = (mm.x - 8.f) * L2E;
    mo.y = (mm.y - 8.f) * L2E;
    mo.z = (mm.z - 8.f) * L2E;
    mo.w = (mm.w - 8.f) * L2E;
    *(float4*)&masks2[idx] = mo;
  }

  bf16x8 qfr[4];
#pragma unroll
  for (int ks = 0; ks < 4; ks++)
    qfr[ks] = *(const bf16x8*)(Qbh + (q0 + w * 32 + m31) * 64 + ks * 16 + hi * 8);

  int r2 = tid >> 3;             // 0..63
  int ch = (tid & 7) * 8;        // 0..56

  {
    uint4 t0 = *(const uint4*)(Kbh + r2 * 64 + ch);
    uint4 t2 = *(const uint4*)(Vbh + r2 * 2048 + ch);
    *(uint4*)&Ks[0][r2][ch] = t0;
    *(uint4*)&Vts[0][r2][ch] = t2;
  }
  uint4 pkv0 = *(const uint4*)(Kbh + (64 + r2) * 64 + ch);
  uint4 pkv2 = *(const uint4*)(Vbh + r2 * 2048 + 64 + ch);

  __syncthreads();

  float lsum = 0.f;
  f32x16 acc_o[2] = {};

  for (int t = 0; t < 32; t++) {
    int cur = t & 1;
    int kt = t * 64;

#pragma unroll
    for (int kb = 0; kb < 2; kb++) {
      f32x16 accs = {};
      __builtin_amdgcn_s_setprio(1);
#pragma unroll
      for (int ks = 0; ks < 4; ks++) {
        bf16x8 kf = *(const bf16x8*)&Ks[cur][kb * 32 + m31][ks * 16 + hi * 8];
        accs = __builtin_amdgcn_mfma_f32_32x32x16_bf16(kf, qfr[ks], accs, 0, 0, 0);
      }
      __builtin_amdgcn_s_setprio(0);

      unsigned int up[4][2];
#pragma unroll
      for (int gg = 0; gg < 4; gg++) {
        float4 m4 = *(const float4*)&masks2[kt + kb * 32 + gg * 8 + hi * 4];
        float p0 = exp2_hw(fmaf(accs[gg * 4 + 0], SC, m4.x));
        float p1 = exp2_hw(fmaf(accs[gg * 4 + 1], SC, m4.y));
        float p2 = exp2_hw(fmaf(accs[gg * 4 + 2], SC, m4.z));
        float p3 = exp2_hw(fmaf(accs[gg * 4 + 3], SC, m4.w));
        lsum += (p0 + p1) + (p2 + p3);
        up[gg][0] = pk_bf16(p0, p1);
        up[gg][1] = pk_bf16(p2, p3);
      }

      // PV with K=16 MFMA: build x16 P-fragments via permlane32_swap.
#pragma unroll
      for (int gp = 0; gp < 2; gp++) {
        union { uint4 u; bf16x8 bv8; } pf;
        unsigned int a0 = up[gp * 2][0], b0 = up[gp * 2 + 1][0];
        unsigned int a1 = up[gp * 2][1], b1 = up[gp * 2 + 1][1];
        asm("v_permlane32_swap_b32 %0, %1" : "+v"(a0), "+v"(b0));
        asm("v_permlane32_swap_b32 %0, %1" : "+v"(a1), "+v"(b1));
        pf.u.x = a0;
        pf.u.y = a1;
        pf.u.z = b0;
        pf.u.w = b1;
        __builtin_amdgcn_s_setprio(1);
#pragma unroll
        for (int db = 0; db < 2; db++) {
          bf16x8 vf = *(const bf16x8*)&Vts[cur][db * 32 + m31][kb * 32 + gp * 16 + hi * 8];
          acc_o[db] = __builtin_amdgcn_mfma_f32_32x32x16_bf16(pf.bv8, vf, acc_o[db], 0, 0, 0);
        }
        __builtin_amdgcn_s_setprio(0);
      }
    }

    if (t < 31) {
      int nb = cur ^ 1;
      *(uint4*)&Ks[nb][r2][ch] = pkv0;
      *(uint4*)&Vts[nb][r2][ch] = pkv2;
      int kn = (kt + 128) & 2047;
      pkv0 = *(const uint4*)(Kbh + (kn + r2) * 64 + ch);
      pkv2 = *(const uint4*)(Vbh + r2 * 2048 + kn + ch);
    }
    __syncthreads();
  }

  lsum += __shfl_xor(lsum, 32);
  lrow[w * 32 + m31] = lsum;
  __asm__ volatile("" ::: "memory");

#pragma unroll
  for (int gg = 0; gg < 4; gg++) {
    float4 l4 = *(const float4*)&lrow[w * 32 + gg * 8 + hi * 4];
    float i0 = rcp_hw(l4.x), i1 = rcp_hw(l4.y), i2 = rcp_hw(l4.z), i3 = rcp_hw(l4.w);
    int qq = q0 + w * 32 + gg * 8 + hi * 4;
#pragma unroll
    for (int db = 0; db < 2; db++) {
      float* obase = out + (b * 2048 + qq) * 1024 + h * 64 + db * 32 + m31;
      obase[0 * 1024] = acc_o[db][gg * 4 + 0] * i0;
      obase[1 * 1024] = acc_o[db][gg * 4 + 1] * i1;
      obase[2 * 1024] = acc_o[db][gg * 4 + 2] * i2;
      obase[3 * 1024] = acc_o[db][gg * 4 + 3] * i3;
    }
  }
}

// ============================================================
extern "C" void kernel_launch(void* const* d_in, const int* in_sizes, int n_in,
                              void* d_out, int out_size, void* d_ws, size_t ws_size,
                              hipStream_t stream) {
  const float* X    = (const float*)d_in[0];
  const float* mask = (const float*)d_in[1];
  const float* Wq = (const float*)d_in[2];
  const float* bq = (const float*)d_in[3];
  const float* Aq = (const float*)d_in[4];
  const float* Bq = (const float*)d_in[5];
  const float* Wk = (const float*)d_in[6];
  const float* bk = (const float*)d_in[7];
  const float* Ak = (const float*)d_in[8];
  const float* Bk = (const float*)d_in[9];
  const float* Wv = (const float*)d_in[10];
  const float* bv = (const float*)d_in[11];
  const float* Av = (const float*)d_in[12];
  const float* Bv = (const float*)d_in[13];

  unsigned short* ws    = (unsigned short*)d_ws;
  unsigned short* Xbf   = ws;
  unsigned short* Weff  = Xbf + 8388608;
  unsigned short* qbuf  = Weff + 3145728;
  unsigned short* kbuf  = qbuf + 8388608;
  unsigned short* vtbuf = kbuf + 8388608;

  prep_kernel<<<dim3(11264), dim3(256), 0, stream>>>(X, Xbf, Wq, Aq, Bq, Wk, Ak, Bk, Wv, Av, Bv, Weff);
  gemm_qkv<<<dim3(1536), dim3(256), 0, stream>>>(Xbf, Weff, bq, bk, bv, qbuf, kbuf, vtbuf);
  attn_kernel<<<dim3(512), dim3(512), 0, stream>>>(qbuf, kbuf, vtbuf, mask, (float*)d_out);
}